// Round 6
// baseline (347.787 us; speedup 1.0000x reference)
//
#include <hip/hip_runtime.h>

#define TH 256          // 4 waves/block
#define BATCHES_PB 8    // 4 waves x 2 batches

typedef float f32x2 __attribute__((ext_vector_type(2)));

__device__ __forceinline__ f32x2 mk2(float a, float b) { f32x2 r; r.x = a; r.y = b; return r; }
__device__ __forceinline__ f32x2 pkfma(f32x2 a, f32x2 b, f32x2 c) {
  asm("v_pk_fma_f32 %0, %1, %2, %3" : "=v"(c) : "v"(a), "v"(b), "0"(c));
  return c;
}
// broadcast b.lo / b.hi to both halves
__device__ __forceinline__ f32x2 pkfma_blo(f32x2 a, f32x2 b, f32x2 c) {
  asm("v_pk_fma_f32 %0, %1, %2, %3 op_sel_hi:[1,0,1]" : "=v"(c) : "v"(a), "v"(b), "0"(c));
  return c;
}
__device__ __forceinline__ f32x2 pkfma_bhi(f32x2 a, f32x2 b, f32x2 c) {
  asm("v_pk_fma_f32 %0, %1, %2, %3 op_sel:[0,1,0] op_sel_hi:[1,1,1]" : "=v"(c) : "v"(a), "v"(b), "0"(c));
  return c;
}

__device__ __forceinline__ float sigm(float x) {
  return __fdividef(1.0f, 1.0f + __expf(-x));
}
__device__ __forceinline__ float fast_tanh(float x) {
  float ex = __expf(2.0f * x);
  return 1.0f - __fdividef(2.0f, ex + 1.0f);
}
__device__ __forceinline__ float gelu_erf(float a) {
  float z = fabsf(a) * 0.70710678118654752440f;
  float t = __fdividef(1.0f, __builtin_fmaf(0.3275911f, z, 1.0f));
  float p = __builtin_fmaf(1.061405429f, t, -1.453152027f);
  p = __builtin_fmaf(p, t, 1.421413741f);
  p = __builtin_fmaf(p, t, -0.284496736f);
  p = __builtin_fmaf(p, t, 0.254829592f);
  p = p * t;
  float e = __expf(-z * z);
  float y = __builtin_fmaf(-p, e, 1.0f);
  return 0.5f * a * (1.0f + copysignf(y, a));
}

#define WAVE_SYNC() asm volatile("s_waitcnt lgkmcnt(0)" ::: "memory")

// load 16 contiguous floats (16B-aligned) into 8 f32x2 regs
__device__ __forceinline__ void ldrow(const float* __restrict__ p, f32x2* w) {
  float4 a = *(const float4*)(p);
  float4 b = *(const float4*)(p + 4);
  float4 c = *(const float4*)(p + 8);
  float4 d = *(const float4*)(p + 12);
  w[0]=mk2(a.x,a.y); w[1]=mk2(a.z,a.w); w[2]=mk2(b.x,b.y); w[3]=mk2(b.z,b.w);
  w[4]=mk2(c.x,c.y); w[5]=mk2(c.z,c.w); w[6]=mk2(d.x,d.y); w[7]=mk2(d.z,d.w);
}
// dot of two 16-float register vectors (+bias)
__device__ __forceinline__ float dotr(const f32x2* w, const f32x2* x, float bias) {
  f32x2 a = mk2(bias, 0.f), b = mk2(0.f, 0.f);
  a = pkfma(w[0], x[0], a); b = pkfma(w[1], x[1], b);
  a = pkfma(w[2], x[2], a); b = pkfma(w[3], x[3], b);
  a = pkfma(w[4], x[4], a); b = pkfma(w[5], x[5], b);
  a = pkfma(w[6], x[6], a); b = pkfma(w[7], x[7], b);
  f32x2 s = a + b;
  return s.x + s.y;
}

// ---------- prep: fold s2s . mix . dec into M2T[64][256] + C0[256] ----------
__global__ void prep_kernel(const float* __restrict__ s2s_w, const float* __restrict__ s2s_b,
                            const float* __restrict__ mix_w, const float* __restrict__ mix_b,
                            const float* __restrict__ dec_w, const float* __restrict__ dec_b,
                            float* __restrict__ M2T, float* __restrict__ C0) {
  const int pix = threadIdx.x;
  const int I = pix >> 4, J = pix & 15;
  const int i = I >> 2, dd = I & 3, j = J >> 2, ee = J & 3;
  const int p = i*4 + j, q = dd*4 + ee;
  float DWrow[64];
  for (int kc = 0; kc < 64; ++kc) {
    float a = 0.f;
    for (int o = 0; o < 16; ++o) a += dec_w[o*16 + q] * mix_w[o*64 + kc];
    DWrow[kc] = a;
  }
  float c0 = dec_b[0];
  for (int o = 0; o < 16; ++o) c0 += dec_w[o*16 + q] * mix_b[o];
  for (int k = 0; k < 4; ++k)
    for (int c = 0; c < 16; ++c) c0 += DWrow[k*16 + c] * s2s_b[c*16 + p];
  C0[pix] = c0;
  for (int k = 0; k < 4; ++k)
    for (int d = 0; d < 16; ++d) {
      float a = 0.f;
      for (int c = 0; c < 16; ++c) a += DWrow[k*16 + c] * s2s_w[(c*16 + p)*16 + d];
      M2T[(k*16 + d)*256 + pix] = a;
    }
}

__launch_bounds__(TH, 3)
__global__ void microslot_kernel(
    const float* __restrict__ frames,
    const float* __restrict__ enc_w, const float* __restrict__ enc_b,
    const float* __restrict__ ln_w,  const float* __restrict__ ln_b,
    const float* __restrict__ slot_mu,
    const float* __restrict__ wq, const float* __restrict__ wk, const float* __restrict__ wv,
    const float* __restrict__ wih, const float* __restrict__ whh,
    const float* __restrict__ bih, const float* __restrict__ bhh,
    const float* __restrict__ g_M2T, const float* __restrict__ g_C0,
    float* __restrict__ out)
{
  __shared__ __align__(16) float W_enc[16*20];   // [c][p]
  __shared__ __align__(16) float W_qT[16*20];    // wq^T: [j][d]
  __shared__ __align__(16) float W_k[16*20];
  __shared__ __align__(16) float W_v[16*20];
  __shared__ __align__(16) float W_ih[48*20];
  __shared__ __align__(16) float W_hh[48*20];
  __shared__ float B_enc[16], LNW[16], LNB[16];
  __shared__ __align__(16) float svb[BATCHES_PB*68];  // svec per batch-row
  __shared__ __align__(16) float SCR[4][2176];        // per-wave scratch (2 batches)

  const int tid = threadIdx.x;

  { int idx = tid; if (idx < 256) W_enc[(idx>>4)*20 + (idx&15)] = enc_w[idx]; }
  { int idx = tid; if (idx < 256) W_qT[(idx&15)*20 + (idx>>4)] = wq[idx]; }
  { int idx = tid; if (idx < 256) W_k [(idx>>4)*20 + (idx&15)] = wk[idx]; }
  { int idx = tid; if (idx < 256) W_v [(idx>>4)*20 + (idx&15)] = wv[idx]; }
  for (int idx = tid; idx < 768; idx += TH) W_ih[(idx>>4)*20 + (idx&15)] = wih[idx];
  for (int idx = tid; idx < 768; idx += TH) W_hh[(idx>>4)*20 + (idx&15)] = whh[idx];
  if (tid < 16) { B_enc[tid] = enc_b[tid]; LNW[tid] = ln_w[tid]; LNB[tid] = ln_b[tid]; }
  __syncthreads();

  const int wid = tid >> 6, lane = tid & 63;
  const int ln = lane & 15, lg = lane >> 4;
  float* S = SCR[wid];
  // scratch offsets (floats)
  constexpr int o_sbA = 0,    o_sbB = 64,  o_tmpA = 128, o_tmpB = 192;
  constexpr int o_xqA = 256,  o_xqB = 576, o_kkA = 896,  o_kkB = 1216;
  constexpr int o_vvA = 1536, o_vvB = 1856;

  float s_regA = slot_mu[lane];
  float s_regB = s_regA;
  const float bi_r = bih[ln], bi_z = bih[16+ln], bi_n = bih[32+ln];
  const float bh_r = bhh[ln], bh_z = bhh[16+ln], bh_n = bhh[32+ln];

  const int i0 = ln >> 2, j0 = ln & 3;
  const size_t bA = (size_t)(blockIdx.x * BATCHES_PB + wid*2);
  const float* fpA = frames + bA * 2048;
  const float* fpB = fpA + 2048;

  for (int st = 0; st < 6; ++st) {
    const int t = st + 1;
    // ---------- P2: conv + GELU + LayerNorm for both batches ----------
    f32x2 pA[8], pB[8];
    #pragma unroll
    for (int a = 0; a < 4; ++a) {
      float4 v = *(const float4*)(fpA + (size_t)t*256 + (4*i0 + a)*16 + 4*j0);
      pA[2*a] = mk2(v.x, v.y); pA[2*a+1] = mk2(v.z, v.w);
      float4 w = *(const float4*)(fpB + (size_t)t*256 + (4*i0 + a)*16 + 4*j0);
      pB[2*a] = mk2(w.x, w.y); pB[2*a+1] = mk2(w.z, w.w);
    }
    float xA[4], xB[4];
    #pragma unroll
    for (int cc = 0; cc < 4; ++cc) {
      int c = 4*lg + cc;
      f32x2 w[8]; ldrow(&W_enc[c*20], w);
      float be = B_enc[c];
      xA[cc] = gelu_erf(dotr(w, pA, be));
      xB[cc] = gelu_erf(dotr(w, pB, be));
    }
    // LayerNorm per batch (reduce over 16 channels: lanes {ln}x4 groups share via lg axis)
    float s1A = xA[0]+xA[1]+xA[2]+xA[3], s2A = xA[0]*xA[0]+xA[1]*xA[1]+xA[2]*xA[2]+xA[3]*xA[3];
    float s1B = xB[0]+xB[1]+xB[2]+xB[3], s2B = xB[0]*xB[0]+xB[1]*xB[1]+xB[2]*xB[2]+xB[3]*xB[3];
    s1A += __shfl_xor(s1A, 16); s1A += __shfl_xor(s1A, 32);
    s2A += __shfl_xor(s2A, 16); s2A += __shfl_xor(s2A, 32);
    s1B += __shfl_xor(s1B, 16); s1B += __shfl_xor(s1B, 32);
    s2B += __shfl_xor(s2B, 16); s2B += __shfl_xor(s2B, 32);
    float muA = s1A * 0.0625f, varA = s2A * 0.0625f - muA*muA, rsA = rsqrtf(varA + 1e-5f);
    float muB = s1B * 0.0625f, varB = s2B * 0.0625f - muB*muB, rsB = rsqrtf(varB + 1e-5f);
    #pragma unroll
    for (int cc = 0; cc < 4; ++cc) {
      int c = 4*lg + cc;
      xA[cc] = (xA[cc]-muA)*rsA*LNW[c] + LNB[c];
      xB[cc] = (xB[cc]-muB)*rsB*LNW[c] + LNB[c];
    }
    *(float4*)&S[o_xqA + ln*20 + 4*lg] = make_float4(xA[0],xA[1],xA[2],xA[3]);
    *(float4*)&S[o_xqB + ln*20 + 4*lg] = make_float4(xB[0],xB[1],xB[2],xB[3]);
    WAVE_SYNC();

    // ---------- P3a: kk, vvT (weight rows shared across batches) ----------
    {
      f32x2 xrA[8], xrB[8];
      ldrow(&S[o_xqA + ln*20], xrA);
      ldrow(&S[o_xqB + ln*20], xrB);
      float kkA4[4], kkB4[4];
      #pragma unroll
      for (int cc = 0; cc < 4; ++cc) {
        int dd = 4*lg + cc;
        f32x2 w[8];
        ldrow(&W_k[dd*20], w);
        kkA4[cc] = dotr(w, xrA, 0.f);
        kkB4[cc] = dotr(w, xrB, 0.f);
        ldrow(&W_v[dd*20], w);
        S[o_vvA + dd*20 + ln] = dotr(w, xrA, 0.f);
        S[o_vvB + dd*20 + ln] = dotr(w, xrB, 0.f);
      }
      *(float4*)&S[o_kkA + ln*20 + 4*lg] = make_float4(kkA4[0],kkA4[1],kkA4[2],kkA4[3]);
      *(float4*)&S[o_kkB + ln*20 + 4*lg] = make_float4(kkB4[0],kkB4[1],kkB4[2],kkB4[3]);
    }
    WAVE_SYNC();

    // ---------- P3b: kq = kk @ wq (shared W_qT rows); hoist vv rows ----------
    f32x2 vvrA[8], vvrB[8];
    {
      f32x2 kA[8], kB[8];
      ldrow(&S[o_kkA + ln*20], kA);
      ldrow(&S[o_kkB + ln*20], kB);
      ldrow(&S[o_vvA + ln*20], vvrA);
      ldrow(&S[o_vvB + ln*20], vvrB);
      float kqA4[4], kqB4[4];
      #pragma unroll
      for (int cc = 0; cc < 4; ++cc) {
        f32x2 w[8]; ldrow(&W_qT[(4*lg+cc)*20], w);
        kqA4[cc] = dotr(w, kA, 0.f);
        kqB4[cc] = dotr(w, kB, 0.f);
      }
      *(float4*)&S[o_xqA + ln*20 + 4*lg] = make_float4(kqA4[0],kqA4[1],kqA4[2],kqA4[3]);
      *(float4*)&S[o_xqB + ln*20 + 4*lg] = make_float4(kqB4[0],kqB4[1],kqB4[2],kqB4[3]);
      // no sync: first P4 sync drains
    }

    // ---------- P4: 3 slot-attention + GRU iterations ----------
    #pragma unroll 1
    for (int it = 0; it < 3; ++it) {
      S[o_sbA + lane] = s_regA;
      S[o_sbB + lane] = s_regB;
      WAVE_SYNC();
      f32x2 hrA[8], hrB[8];
      ldrow(&S[o_sbA + lg*16], hrA);
      ldrow(&S[o_sbB + lg*16], hrB);
      f32x2 kw[8];
      ldrow(&S[o_xqA + ln*20], kw);
      float lA = 0.25f * dotr(kw, hrA, 0.f);
      ldrow(&S[o_xqB + ln*20], kw);
      float lB = 0.25f * dotr(kw, hrB, 0.f);
      // softmax over K=4 slots (|logits| small by construction)
      float eA = __expf(lA), eB = __expf(lB);
      float seA = eA + __shfl_xor(eA, 16); seA += __shfl_xor(seA, 32);
      float seB = eB + __shfl_xor(eB, 16); seB += __shfl_xor(seB, 32);
      S[o_tmpA + lane] = __fdividef(eA, seA);
      S[o_tmpB + lane] = __fdividef(eB, seB);
      WAVE_SYNC();
      f32x2 aA[8], aB[8];
      ldrow(&S[o_tmpA + lg*16], aA);
      ldrow(&S[o_tmpB + lg*16], aB);
      float uA = dotr(aA, vvrA, 0.f);
      float uB = dotr(aB, vvrB, 0.f);
      S[o_tmpA + lane] = uA;   // whole wave's reads complete before these writes
      S[o_tmpB + lane] = uB;
      WAVE_SYNC();
      f32x2 urA[8], urB[8];
      ldrow(&S[o_tmpA + lg*16], urA);
      ldrow(&S[o_tmpB + lg*16], urB);
      // GRU (torch semantics); weight rows read once, used for both batches
      f32x2 girA = mk2(bi_r,0.f), gizA = mk2(bi_z,0.f), ginA = mk2(bi_n,0.f);
      f32x2 ghrA = mk2(bh_r,0.f), ghzA = mk2(bh_z,0.f), ghnA = mk2(bh_n,0.f);
      f32x2 girB = mk2(bi_r,0.f), gizB = mk2(bi_z,0.f), ginB = mk2(bi_n,0.f);
      f32x2 ghrB = mk2(bh_r,0.f), ghzB = mk2(bh_z,0.f), ghnB = mk2(bh_n,0.f);
      #pragma unroll
      for (int qd = 0; qd < 4; ++qd) {
        float4 wr = *(const float4*)&W_ih[(   ln)*20 + 4*qd];
        float4 wz = *(const float4*)&W_ih[(16+ln)*20 + 4*qd];
        float4 wn = *(const float4*)&W_ih[(32+ln)*20 + 4*qd];
        float4 vr = *(const float4*)&W_hh[(   ln)*20 + 4*qd];
        float4 vz = *(const float4*)&W_hh[(16+ln)*20 + 4*qd];
        float4 vn = *(const float4*)&W_hh[(32+ln)*20 + 4*qd];
        f32x2 wrl = mk2(wr.x,wr.y), wrh = mk2(wr.z,wr.w);
        f32x2 wzl = mk2(wz.x,wz.y), wzh = mk2(wz.z,wz.w);
        f32x2 wnl = mk2(wn.x,wn.y), wnh = mk2(wn.z,wn.w);
        f32x2 vrl = mk2(vr.x,vr.y), vrh = mk2(vr.z,vr.w);
        f32x2 vzl = mk2(vz.x,vz.y), vzh = mk2(vz.z,vz.w);
        f32x2 vnl = mk2(vn.x,vn.y), vnh = mk2(vn.z,vn.w);
        girA = pkfma(wrl, urA[2*qd], girA); girA = pkfma(wrh, urA[2*qd+1], girA);
        girB = pkfma(wrl, urB[2*qd], girB); girB = pkfma(wrh, urB[2*qd+1], girB);
        gizA = pkfma(wzl, urA[2*qd], gizA); gizA = pkfma(wzh, urA[2*qd+1], gizA);
        gizB = pkfma(wzl, urB[2*qd], gizB); gizB = pkfma(wzh, urB[2*qd+1], gizB);
        ginA = pkfma(wnl, urA[2*qd], ginA); ginA = pkfma(wnh, urA[2*qd+1], ginA);
        ginB = pkfma(wnl, urB[2*qd], ginB); ginB = pkfma(wnh, urB[2*qd+1], ginB);
        ghrA = pkfma(vrl, hrA[2*qd], ghrA); ghrA = pkfma(vrh, hrA[2*qd+1], ghrA);
        ghrB = pkfma(vrl, hrB[2*qd], ghrB); ghrB = pkfma(vrh, hrB[2*qd+1], ghrB);
        ghzA = pkfma(vzl, hrA[2*qd], ghzA); ghzA = pkfma(vzh, hrA[2*qd+1], ghzA);
        ghzB = pkfma(vzl, hrB[2*qd], ghzB); ghzB = pkfma(vzh, hrB[2*qd+1], ghzB);
        ghnA = pkfma(vnl, hrA[2*qd], ghnA); ghnA = pkfma(vnh, hrA[2*qd+1], ghnA);
        ghnB = pkfma(vnl, hrB[2*qd], ghnB); ghnB = pkfma(vnh, hrB[2*qd+1], ghnB);
      }
      {
        float rg = sigm((girA.x+girA.y) + (ghrA.x+ghrA.y));
        float zg = sigm((gizA.x+gizA.y) + (ghzA.x+ghzA.y));
        float nh = fast_tanh((ginA.x+ginA.y) + rg*(ghnA.x+ghnA.y));
        s_regA = (1.f - zg)*nh + zg*s_regA;
      }
      {
        float rg = sigm((girB.x+girB.y) + (ghrB.x+ghrB.y));
        float zg = sigm((gizB.x+gizB.y) + (ghzB.x+ghzB.y));
        float nh = fast_tanh((ginB.x+ginB.y) + rg*(ghnB.x+ghnB.y));
        s_regB = (1.f - zg)*nh + zg*s_regB;
      }
    }

    // ---------- P5: block-cooperative decode via folded M2T ----------
    svb[(wid*2+0)*68 + lane] = s_regA;
    svb[(wid*2+1)*68 + lane] = s_regB;
    __syncthreads();
    {
      const int rb = tid >> 5, c32 = tid & 31;   // one batch-row per 32 threads
      const float* svp = &svb[rb*68];
      const int pix1 = 4*c32, pix2 = pix1 + 128;
      const float* m1p = g_M2T + pix1;
      const float* m2p = g_M2T + pix2;
      float4 c01 = *(const float4*)(g_C0 + pix1);
      float4 c02 = *(const float4*)(g_C0 + pix2);
      f32x2 a01 = mk2(c01.x, c01.y), a23 = mk2(c01.z, c01.w);
      f32x2 b01 = mk2(c02.x, c02.y), b23 = mk2(c02.z, c02.w);
      #pragma unroll 4
      for (int q4 = 0; q4 < 16; ++q4) {
        float4 sv = *(const float4*)(svp + 4*q4);
        f32x2 svA = mk2(sv.x, sv.y), svB = mk2(sv.z, sv.w);
        float4 m0 = *(const float4*)(m1p + (4*q4+0)*256);
        float4 m1 = *(const float4*)(m1p + (4*q4+1)*256);
        float4 m2 = *(const float4*)(m1p + (4*q4+2)*256);
        float4 m3 = *(const float4*)(m1p + (4*q4+3)*256);
        a01 = pkfma_blo(mk2(m0.x,m0.y), svA, a01); a23 = pkfma_blo(mk2(m0.z,m0.w), svA, a23);
        a01 = pkfma_bhi(mk2(m1.x,m1.y), svA, a01); a23 = pkfma_bhi(mk2(m1.z,m1.w), svA, a23);
        a01 = pkfma_blo(mk2(m2.x,m2.y), svB, a01); a23 = pkfma_blo(mk2(m2.z,m2.w), svB, a23);
        a01 = pkfma_bhi(mk2(m3.x,m3.y), svB, a01); a23 = pkfma_bhi(mk2(m3.z,m3.w), svB, a23);
        float4 n0 = *(const float4*)(m2p + (4*q4+0)*256);
        float4 n1 = *(const float4*)(m2p + (4*q4+1)*256);
        float4 n2 = *(const float4*)(m2p + (4*q4+2)*256);
        float4 n3 = *(const float4*)(m2p + (4*q4+3)*256);
        b01 = pkfma_blo(mk2(n0.x,n0.y), svA, b01); b23 = pkfma_blo(mk2(n0.z,n0.w), svA, b23);
        b01 = pkfma_bhi(mk2(n1.x,n1.y), svA, b01); b23 = pkfma_bhi(mk2(n1.z,n1.w), svA, b23);
        b01 = pkfma_blo(mk2(n2.x,n2.y), svB, b01); b23 = pkfma_blo(mk2(n2.z,n2.w), svB, b23);
        b01 = pkfma_bhi(mk2(n3.x,n3.y), svB, b01); b23 = pkfma_bhi(mk2(n3.z,n3.w), svB, b23);
      }
      const size_t ob = (size_t)(blockIdx.x*BATCHES_PB + rb)*(6*256) + (size_t)st*256;
      *(float4*)(out + ob + pix1) = make_float4(sigm(a01.x), sigm(a01.y), sigm(a23.x), sigm(a23.y));
      *(float4*)(out + ob + pix2) = make_float4(sigm(b01.x), sigm(b01.y), sigm(b23.x), sigm(b23.y));
    }
    __syncthreads();
  }
}

extern "C" void kernel_launch(void* const* d_in, const int* in_sizes, int n_in,
                              void* d_out, int out_size, void* d_ws, size_t ws_size,
                              hipStream_t stream) {
  const float* frames  = (const float*)d_in[0];
  const float* enc_w   = (const float*)d_in[1];
  const float* enc_b   = (const float*)d_in[2];
  const float* ln_w    = (const float*)d_in[3];
  const float* ln_b    = (const float*)d_in[4];
  const float* slot_mu = (const float*)d_in[5];
  const float* wq      = (const float*)d_in[6];
  const float* wk      = (const float*)d_in[7];
  const float* wv      = (const float*)d_in[8];
  const float* wih     = (const float*)d_in[9];
  const float* whh     = (const float*)d_in[10];
  const float* bih     = (const float*)d_in[11];
  const float* bhh     = (const float*)d_in[12];
  const float* s2s_w   = (const float*)d_in[13];
  const float* s2s_b   = (const float*)d_in[14];
  const float* mix_w   = (const float*)d_in[15];
  const float* mix_b   = (const float*)d_in[16];
  const float* dec_w   = (const float*)d_in[17];
  const float* dec_b   = (const float*)d_in[18];
  float* out = (float*)d_out;

  float* g_M2T = (float*)d_ws;            // 64*256 floats
  float* g_C0  = g_M2T + 64*256;          // 256 floats

  hipLaunchKernelGGL(prep_kernel, dim3(1), dim3(256), 0, stream,
                     s2s_w, s2s_b, mix_w, mix_b, dec_w, dec_b, g_M2T, g_C0);

  const int B = 16384;
  hipLaunchKernelGGL(microslot_kernel, dim3(B / BATCHES_PB), dim3(TH), 0, stream,
                     frames, enc_w, enc_b, ln_w, ln_b, slot_mu, wq, wk, wv,
                     wih, whh, bih, bhh, g_M2T, g_C0, out);
}